// Round 13
// baseline (278.260 us; speedup 1.0000x reference)
//
#include <hip/hip_runtime.h>
#include <hip/hip_bf16.h>
#include <hip/hip_fp16.h>

#define BATCH 8
#define NSEQ 1024
#define DIMM 448
#define NHEAD 7
#define HDIM 64
#define MROWS (BATCH*NSEQ)   // 8192
#define KDIM 448
#define SCALE_F 0.125f
// Padded region stride (shorts) for packed K/V/bias streams.
#define PSTR 66048

typedef short short8 __attribute__((ext_vector_type(8)));
typedef float floatx16 __attribute__((ext_vector_type(16)));

#define MFMA32(a,b,c) __builtin_amdgcn_mfma_f32_32x32x16_bf16(a,b,c,0,0,0)

__device__ __forceinline__ unsigned short f2bf(float f){
    __hip_bfloat16 h = __float2bfloat16(f);
    return *reinterpret_cast<unsigned short*>(&h);
}
__device__ __forceinline__ float bf2f(unsigned short u){
    __hip_bfloat16 h; *reinterpret_cast<unsigned short*>(&h) = u;
    return __bfloat162float(h);
}
__device__ __forceinline__ float h2f(unsigned short u){
    __half h; *reinterpret_cast<unsigned short*>(&h) = u;
    return __half2float(h);
}
__device__ __forceinline__ unsigned short f2h(float f){
    __half h = __float2half(f);
    return *reinterpret_cast<unsigned short*>(&h);
}

// ---------------------------------------------------------------------------
// prep_min: conversions gemm1 depends on + split-k flag zeroing.
//   [0,3584)     : x fp32 -> xh bf16 (1 float4/thread)
//   [3584,3780)  : wqv [448][896] -> wqvTh [896][448] bf16 (4x 64-thr units)
//   [3780]       : zero the 896 attn split-k flags (workspace is POISONED
//                  between harness iterations — cannot assume zero).
// ---------------------------------------------------------------------------
__global__ __launch_bounds__(256)
void prep_min(const float* __restrict__ x, const float* __restrict__ wqv,
              unsigned short* __restrict__ xh, unsigned short* __restrict__ wqvTh,
              unsigned* __restrict__ flags)
{
    const int bx = blockIdx.x, tid = threadIdx.x;
    if (bx < 3584) {                         // x -> bf16
        int i = bx*256 + tid;
        float4 v = ((const float4*)x)[i];
        ((ushort4*)xh)[i] = make_ushort4(f2bf(v.x), f2bf(v.y), f2bf(v.z), f2bf(v.w));
    } else if (bx < 3780) {                  // wqv transpose, single bf16
        int lid = (bx-3584)*4 + (tid>>6);    // 0..783 = kc(56) x ng(14)
        int kc = lid % 56, ng = lid / 56;
        int n = ng*64 + (tid&63);
        unsigned short h[8];
#pragma unroll
        for (int j = 0; j < 8; ++j) h[j] = f2bf(wqv[(size_t)(kc*8+j)*896 + n]);
        size_t o = (size_t)n*KDIM + kc*8;
        *(ushort4*)(wqvTh + o)     = make_ushort4(h[0],h[1],h[2],h[3]);
        *(ushort4*)(wqvTh + o + 4) = make_ushort4(h[4],h[5],h[6],h[7]);
    } else {                                 // zero split-k flags
        for (int i = tid; i < 896; i += 256) flags[i] = 0u;
    }
}

// ---------------------------------------------------------------------------
// gemm1_fused: gemm1 (448 blocks) + bias-prep (1792) + ek-pack (448) +
// wout-split (112) in ONE launch = 2800 blocks.
// ---------------------------------------------------------------------------
__global__ __launch_bounds__(256, 2)
void gemm1_fused(const unsigned short* __restrict__ Ah, const unsigned short* __restrict__ Bh,
                 const float* __restrict__ ek, const float* __restrict__ eb,
                 const float* __restrict__ wout,
                 unsigned short* __restrict__ qd, unsigned short* __restrict__ vTd,
                 unsigned short* __restrict__ ekh, unsigned short* __restrict__ bp,
                 unsigned short* __restrict__ woTh, unsigned short* __restrict__ woTl)
{
    __shared__ float T[2][64][33];
    const int bx = blockIdx.x, tid = threadIdx.x;

    if (bx < 448) {                          // ---- gemm1 (proven code) ----
        const int w = tid >> 6, lane = tid & 63;
        const int lq = lane & 31, lh = lane >> 5;
        const int xb = bx & 31, y = bx >> 5;
        const int m0 = (xb*4 + w) * 64;
        const int n0 = y * 64;
        const unsigned short* aB = Ah + (size_t)(m0 + lq)*KDIM + lh*8;
        const unsigned short* bB = Bh + (size_t)(n0 + lq)*KDIM + lh*8;

        floatx16 acc[2][2] = {};
        short8 aR[2][2][2], bR[2][2][2];
#define LD1(kt, par) {                                                        \
    _Pragma("unroll") for (int fm = 0; fm < 2; ++fm)                          \
    _Pragma("unroll") for (int c = 0; c < 2; ++c) {                           \
        aR[par][fm][c] = *(const short8*)(aB + (size_t)fm*32*KDIM + (kt)*32 + c*16); \
        bR[par][fm][c] = *(const short8*)(bB + (size_t)fm*32*KDIM + (kt)*32 + c*16); } }

        LD1(0, 0)
#pragma unroll
        for (int kt = 0; kt < 14; ++kt) {
            const int par = kt & 1;
            if (kt < 13) LD1(kt+1, par^1)
#pragma unroll
            for (int c = 0; c < 2; ++c)
#pragma unroll
                for (int fm = 0; fm < 2; ++fm)
#pragma unroll
                    for (int fn = 0; fn < 2; ++fn)
                        acc[fm][fn] = MFMA32(aR[par][fm][c], bR[par][fn][c], acc[fm][fn]);
        }
#undef LD1

        if (y < NHEAD) {
#pragma unroll
            for (int fm = 0; fm < 2; ++fm)
#pragma unroll
                for (int fn = 0; fn < 2; ++fn) {
                    const int d = fn*32 + lq;
#pragma unroll
                    for (int r = 0; r < 16; ++r) {
                        const int gm = m0 + fm*32 + (r&3) + 8*(r>>2) + 4*lh;
                        const int b = gm >> 10, ns = gm & 1023;
                        qd[((size_t)((b*NHEAD + y)*NSEQ + ns))*HDIM + d] = f2bf(acc[fm][fn][r]);
                    }
                }
        } else {
            const int head = y - NHEAD;
#pragma unroll
            for (int fm = 0; fm < 2; ++fm) {
                const int gm0 = m0 + fm*32;
                const int b = gm0 >> 10, mm = (gm0 & 1023) >> 5;
                unsigned short* base = vTd + (size_t)(b*NHEAD + head)*PSTR + (size_t)mm*2048;
#pragma unroll
                for (int fn = 0; fn < 2; ++fn)
#pragma unroll
                    for (int rq = 0; rq < 4; ++rq) {
                        const int u = (rq>>1)*2 + fn;
                        const int lanep = (rq&1)*32 + lq;
                        *(ushort4*)(base + u*512 + lanep*8 + 4*lh) = make_ushort4(
                            f2bf(acc[fm][fn][rq*4+0]), f2bf(acc[fm][fn][rq*4+1]),
                            f2bf(acc[fm][fn][rq*4+2]), f2bf(acc[fm][fn][rq*4+3]));
                    }
            }
        }
    } else if (bx < 2240) {                  // ---- bias prep (padded) ----
        const int sub = tid >> 7, st = tid & 127;
        const int lid = (bx-448)*2 + sub;    // 0..3583
        const int mt = lid & 31, qt = (lid>>5) & 15, h = lid >> 9;
#pragma unroll
        for (int it = 0; it < 4; ++it) {
            int idx = it*128 + st;
            int row = idx >> 3, c4 = (idx & 7)*4;
            float4 v = *(const float4*)(eb + ((size_t)(h*NSEQ + qt*64 + row))*NSEQ + mt*32 + c4);
            T[sub][row][c4+0]=v.x; T[sub][row][c4+1]=v.y;
            T[sub][row][c4+2]=v.z; T[sub][row][c4+3]=v.w;
        }
        __syncthreads();
        const int g2 = st >> 6, lane = st & 63;
        const int lq = lane & 31, quad = lane >> 5;
        const int q = g2*32 + lq;
        unsigned short* dst = bp + (size_t)(h*16 + qt)*PSTR
                            + (size_t)(mt*4 + g2*2)*512 + lane*8;
#pragma unroll
        for (int jj = 0; jj < 2; ++jj) {
            unsigned short o[8];
#pragma unroll
            for (int t = 0; t < 8; ++t) {
                int m = (t&3) + 8*(t>>2) + 16*jj + 4*quad;
                o[t] = f2h(T[sub][q][m] * SCALE_F);
            }
            *(ushort4*)(dst + jj*512)     = make_ushort4(o[0],o[1],o[2],o[3]);
            *(ushort4*)(dst + jj*512 + 4) = make_ushort4(o[4],o[5],o[6],o[7]);
        }
    } else if (bx < 2688) {                  // ---- ek -> kP (packed, padded) ----
        int i = (bx-2240)*256 + tid;         // 0..114687 chunk of 4 shorts
        const int h  = i >> 14, mm = (i >> 9) & 31, c = (i >> 7) & 3;
        const int ln = (i >> 1) & 63, jh = i & 1;
        const float* src = ek + ((size_t)(h*NSEQ) + mm*32 + (ln & 31))*HDIM
                              + c*16 + (ln >> 5)*8 + jh*4;
        float4 v = *(const float4*)src;
        unsigned short* dst = ekh + (size_t)h*PSTR + (size_t)(i & 16383)*4;
        *(ushort4*)dst = make_ushort4(f2bf(v.x), f2bf(v.y), f2bf(v.z), f2bf(v.w));
    } else {                                 // ---- wout transpose, split hi/lo ----
        int lid = (bx-2688)*4 + (tid>>6);    // 0..447 = kc(56) x ng(8)
        int kc = lid % 56, ng = lid / 56;
        int n = ng*64 + (tid&63);
        ushort4 h0={0,0,0,0}, h1={0,0,0,0}, l0={0,0,0,0}, l1={0,0,0,0};
        if (n < DIMM) {
            unsigned short h[8], l[8];
#pragma unroll
            for (int j = 0; j < 8; ++j) {
                float f = wout[(size_t)(kc*8+j)*DIMM + n];
                h[j] = f2bf(f); l[j] = f2bf(f - bf2f(h[j]));
            }
            h0 = make_ushort4(h[0],h[1],h[2],h[3]); h1 = make_ushort4(h[4],h[5],h[6],h[7]);
            l0 = make_ushort4(l[0],l[1],l[2],l[3]); l1 = make_ushort4(l[4],l[5],l[6],l[7]);
        }
        size_t o = (size_t)n*KDIM + kc*8;
        *(ushort4*)(woTh + o) = h0; *(ushort4*)(woTh + o + 4) = h1;
        *(ushort4*)(woTl + o) = l0; *(ushort4*)(woTl + o + 4) = l1;
    }
}

// ---------------------------------------------------------------------------
// attn_skc: attn_half with the COMBINE FUSED via split-k semaphore.
// Each (head,qt,b) tile has 2 half-blocks. Both write fp32 partials, then
// __threadfence() + atomicAdd(flag[tile],1). The SECOND finisher (old==1,
// guaranteed already-executing sibling -> no spin, no dispatch-order
// assumption) combines its own REGISTERS + the sibling's partials from
// memory and writes aoh/aol (same math as the old attn_combine; f32 add
// commutativity makes winner-order bit-exact). Deletes the combine kernel
// (+launch gap) and the winner's 15MB self-re-read; combine work overlaps
// other blocks' main loops.
// ---------------------------------------------------------------------------
__global__ __launch_bounds__(256, 2)
void attn_skc(const unsigned short* __restrict__ qh_g, const unsigned short* __restrict__ vTh,
              const unsigned short* __restrict__ ekh, const unsigned short* __restrict__ bp,
              float4* __restrict__ opart, float2* __restrict__ lspart,
              unsigned* __restrict__ flags,
              unsigned short* __restrict__ aoh, unsigned short* __restrict__ aol)
{
    __shared__ float linv[4][2][32];
    const int tid = threadIdx.x;
    const int w = tid >> 6, lane = tid & 63;
    const int lq = lane & 31, lh = lane >> 5;

    // bijective XCD swizzle: 448 blocks, 56 per XCD
    const int orig = blockIdx.x;
    const int wg = (orig & 7)*56 + (orig >> 3);
    const int half = wg & 1, bq = (wg >> 1) & 1, qt = (wg >> 2) & 15, head = wg >> 6;
    const int b = bq*4 + w;
    const int bh = b*NHEAD + head;
    const int mBeg = half*16;

    short8 qf[2][4];
#pragma unroll
    for (int g2 = 0; g2 < 2; ++g2)
#pragma unroll
        for (int c = 0; c < 4; ++c)
            qf[g2][c] = *(const short8*)(qh_g +
                ((size_t)(bh*NSEQ) + qt*64 + g2*32 + lq)*HDIM + c*16 + lh*8);

    const unsigned short* kB = ekh + (size_t)head*PSTR + lane*8;              // b-indep, packed
    const unsigned short* vB = vTh + (size_t)bh*PSTR + lane*8;                // per-b, packed
    const unsigned short* bB = bp + (size_t)(head*16 + qt)*PSTR + lane*8;     // b-indep, packed

    short8 kR[2][4], vR[2][4], bR[2][4];
#define PREF(J, par) { const int mm = ((J) < mBeg+16) ? (J) : mBeg;            \
    _Pragma("unroll") for (int c = 0; c < 4; ++c)                              \
        kR[par][c] = *(const short8*)(kB + (size_t)mm*2048 + c*512);           \
    _Pragma("unroll") for (int u = 0; u < 4; ++u)                              \
        vR[par][u] = *(const short8*)(vB + (size_t)mm*2048 + u*512);           \
    _Pragma("unroll") for (int u = 0; u < 4; ++u)                              \
        bR[par][u] = *(const short8*)(bB + (size_t)mm*2048 + u*512); }

    floatx16 O[2][2] = {};
    float ls[2] = {0.f, 0.f};

#define SEC(J, par, nxt) {                                                     \
    PREF((J)+1, nxt)                                                           \
    _Pragma("unroll") for (int g2 = 0; g2 < 2; ++g2) {                         \
        floatx16 S = {};                                                       \
        _Pragma("unroll") for (int c = 0; c < 4; ++c)                          \
            S = MFMA32(kR[par][c], qf[g2][c], S);                              \
        float pv[16];                                                          \
        _Pragma("unroll") for (int i = 0; i < 16; ++i) {                       \
            float bs = h2f((unsigned short)bR[par][g2*2 + (i>>3)][i&7]);       \
            pv[i] = __expf(fmaf(S[i], SCALE_F, bs));                           \
            ls[g2] += pv[i];                                                   \
        }                                                                      \
        unsigned wpk[8];                                                       \
        _Pragma("unroll") for (int u = 0; u < 8; ++u)                          \
            wpk[u] = (unsigned)f2bf(pv[2*u]) | ((unsigned)f2bf(pv[2*u+1]) << 16); \
        asm("v_permlane32_swap_b32 %0, %1" : "+v"(wpk[0]), "+v"(wpk[2]));      \
        asm("v_permlane32_swap_b32 %0, %1" : "+v"(wpk[1]), "+v"(wpk[3]));      \
        asm("v_permlane32_swap_b32 %0, %1" : "+v"(wpk[4]), "+v"(wpk[6]));      \
        asm("v_permlane32_swap_b32 %0, %1" : "+v"(wpk[5]), "+v"(wpk[7]));      \
        union U8 { unsigned u[4]; short8 s; };                                 \
        U8 pa0, pa1;                                                           \
        pa0.u[0]=wpk[0]; pa0.u[1]=wpk[1]; pa0.u[2]=wpk[2]; pa0.u[3]=wpk[3];    \
        pa1.u[0]=wpk[4]; pa1.u[1]=wpk[5]; pa1.u[2]=wpk[6]; pa1.u[3]=wpk[7];    \
        O[g2][0] = MFMA32(pa0.s, vR[par][0], O[g2][0]);                        \
        O[g2][1] = MFMA32(pa0.s, vR[par][1], O[g2][1]);                        \
        O[g2][0] = MFMA32(pa1.s, vR[par][2], O[g2][0]);                        \
        O[g2][1] = MFMA32(pa1.s, vR[par][3], O[g2][1]);                        \
    } }

    PREF(mBeg, 0)
    for (int jj = 0; jj < 8; ++jj) {
        SEC(mBeg+2*jj,   0, 1)
        SEC(mBeg+2*jj+1, 1, 0)
    }
#undef SEC
#undef PREF

    // ---- publish partials ----
    const int tile = (head*16 + qt)*8 + b;
    const int wid = tile*2 + half;
    float4* ob = opart + (size_t)wid*1024;
#pragma unroll
    for (int g2 = 0; g2 < 2; ++g2)
#pragma unroll
        for (int fn = 0; fn < 2; ++fn)
#pragma unroll
            for (int r4 = 0; r4 < 4; ++r4)
                ob[((g2*2+fn)*4 + r4)*64 + lane] = make_float4(
                    O[g2][fn][r4*4+0], O[g2][fn][r4*4+1],
                    O[g2][fn][r4*4+2], O[g2][fn][r4*4+3]);
    lspart[(size_t)wid*64 + lane] = make_float2(ls[0], ls[1]);

    // ---- split-k semaphore: second finisher combines ----
    __threadfence();
    unsigned old = 0;
    if (lane == 0) old = atomicAdd(&flags[tile], 1u);
    old = __shfl(old, 0);
    if (old == 1) {
        __threadfence();                      // acquire: sibling's stores visible
        const int sib = tile*2 + (1 - half);
        const float2 lb = lspart[(size_t)sib*64 + lane];
        float lt0p = ls[0] + lb.x, lt1p = ls[1] + lb.y;
        float lt0 = lt0p + __shfl_xor(lt0p, 32);
        float lt1 = lt1p + __shfl_xor(lt1p, 32);
        if (lh == 0) { linv[w][0][lq] = 1.f/lt0; linv[w][1][lq] = 1.f/lt1; }

        const float4* oa = opart + (size_t)sib*1024;
#pragma unroll
        for (int g2 = 0; g2 < 2; ++g2)
#pragma unroll
            for (int fn = 0; fn < 2; ++fn)
#pragma unroll
                for (int r4 = 0; r4 < 4; ++r4) {
                    const int ch = ((g2*2+fn)*4 + r4)*64 + lane;
                    float4 vb = oa[ch];
                    float s[4] = {O[g2][fn][r4*4+0]+vb.x, O[g2][fn][r4*4+1]+vb.y,
                                  O[g2][fn][r4*4+2]+vb.z, O[g2][fn][r4*4+3]+vb.w};
#pragma unroll
                    for (int j = 0; j < 4; ++j) {
                        const int qr = j + 8*r4 + 4*lh;
                        const float inv = linv[w][g2][qr];
                        const size_t o = ((size_t)(b*NSEQ) + qt*64 + g2*32 + qr)*DIMM
                                       + head*HDIM + fn*32 + lq;
                        float v = s[j]*inv;
                        unsigned short h0 = f2bf(v);
                        aoh[o] = h0;  aol[o] = f2bf(v - bf2f(h0));
                    }
                }
    }
}

// ---------------------------------------------------------------------------
// gemm2_grp: out = ao @ w_out + b_out, split-2 (3-term), REGISTER-ONLY.
// ---------------------------------------------------------------------------
__global__ __launch_bounds__(128, 2)
void gemm2_grp(const unsigned short* __restrict__ Ah, const unsigned short* __restrict__ Al,
               const unsigned short* __restrict__ Bh, const unsigned short* __restrict__ Bl,
               const float* __restrict__ bias, float* __restrict__ out)
{
    const int tid = threadIdx.x;
    const int w = tid >> 6, lane = tid & 63;
    const int lq = lane & 31, lh = lane >> 5;
    const int m0 = (blockIdx.x*2 + w) * 64;
    const int n0 = blockIdx.y * 64;
    const unsigned short* aBh = Ah + (size_t)(m0 + lq)*KDIM + lh*8;
    const unsigned short* aBl = Al + (size_t)(m0 + lq)*KDIM + lh*8;
    const unsigned short* bBh = Bh + (size_t)(n0 + lq)*KDIM + lh*8;
    const unsigned short* bBl = Bl + (size_t)(n0 + lq)*KDIM + lh*8;

    floatx16 acc[2][2] = {};
    short8 aH[2][2][2], aL[2][2][2], bH[2][2][2], bL[2][2][2];
#define LD2(kt, par) {                                                        \
    _Pragma("unroll") for (int fm = 0; fm < 2; ++fm)                          \
    _Pragma("unroll") for (int c = 0; c < 2; ++c) {                           \
        const size_t off = (size_t)fm*32*KDIM + (kt)*32 + c*16;               \
        aH[par][fm][c] = *(const short8*)(aBh + off);                         \
        aL[par][fm][c] = *(const short8*)(aBl + off);                         \
        bH[par][fm][c] = *(const short8*)(bBh + off);                         \
        bL[par][fm][c] = *(const short8*)(bBl + off); } }

    LD2(0, 0)
#pragma unroll
    for (int kt = 0; kt < 14; ++kt) {
        const int par = kt & 1;
        if (kt < 13) LD2(kt+1, par^1)
#pragma unroll
        for (int c = 0; c < 2; ++c)
#pragma unroll
            for (int fm = 0; fm < 2; ++fm)
#pragma unroll
                for (int fn = 0; fn < 2; ++fn) {
                    acc[fm][fn] = MFMA32(aH[par][fm][c], bH[par][fn][c], acc[fm][fn]);
                    acc[fm][fn] = MFMA32(aL[par][fm][c], bH[par][fn][c], acc[fm][fn]);
                    acc[fm][fn] = MFMA32(aH[par][fm][c], bL[par][fn][c], acc[fm][fn]);
                }
    }
#undef LD2

#pragma unroll
    for (int fm = 0; fm < 2; ++fm)
#pragma unroll
        for (int fn = 0; fn < 2; ++fn) {
            const int gn = n0 + fn*32 + lq;
            const float bv = bias[gn];
#pragma unroll
            for (int r = 0; r < 16; ++r) {
                const int gm = m0 + fm*32 + (r&3) + 8*(r>>2) + 4*lh;
                out[(size_t)gm*DIMM + gn] = acc[fm][fn][r] + bv;
            }
        }
}

// ---------------------------------------------------------------------------
extern "C" void kernel_launch(void* const* d_in, const int* in_sizes, int n_in,
                              void* d_out, int out_size, void* d_ws, size_t ws_size,
                              hipStream_t stream)
{
    const float* x    = (const float*)d_in[0];
    const float* wqv  = (const float*)d_in[1];
    const float* ek   = (const float*)d_in[2];
    const float* eb   = (const float*)d_in[3];
    const float* wout = (const float*)d_in[4];
    const float* bout = (const float*)d_in[5];
    float* out = (float*)d_out;

    const size_t MK = (size_t)MROWS*KDIM;        // 3,670,016
    unsigned short* p = (unsigned short*)d_ws;
    unsigned short* xh    = p;  p += MK;
    unsigned short* wqvTh = p;  p += (size_t)896*KDIM;
    unsigned short* woTh  = p;  p += (size_t)512*KDIM;
    unsigned short* woTl  = p;  p += (size_t)512*KDIM;
    unsigned short* ekh   = p;  p += (size_t)NHEAD*PSTR;             // kP padded
    unsigned short* qh    = p;  p += MK;
    unsigned short* vTh   = p;  p += (size_t)BATCH*NHEAD*PSTR;       // vP padded
    unsigned short* bp    = p;  p += (size_t)NHEAD*16*PSTR;          // fp16 padded
    unsigned short* aoh   = p;  p += MK;
    unsigned short* aol   = p;  p += MK;
    // fp32 partials (16B-aligned: preceding offsets are multiples of 8 shorts)
    float4* opart  = (float4*)p;                 // 1792 * 1024 float4 = 29.4 MB
    p += (size_t)1792*1024*8;
    float2* lspart = (float2*)p;                 // 1792 * 64 float2 = 0.9 MB
    p += (size_t)1792*64*4;
    unsigned* flags = (unsigned*)p;              // 896 split-k semaphores
    p += (size_t)896*2;

    prep_min<<<3781, 256, 0, stream>>>(x, wqv, xh, wqvTh, flags);
    gemm1_fused<<<2800, 256, 0, stream>>>(xh, wqvTh, ek, eb, wout,
                                          qh, vTh, ekh, bp, woTh, woTl);
    attn_skc<<<448, 256, 0, stream>>>(qh, vTh, ekh, bp, opart, lspart, flags, aoh, aol);
    gemm2_grp<<<dim3(64, 7), 128, 0, stream>>>(aoh, aol, woTh, woTl, bout, out);
}

// Round 15
// 192.626 us; speedup vs baseline: 1.4446x; 1.4446x over previous
//
#include <hip/hip_runtime.h>
#include <hip/hip_bf16.h>
#include <hip/hip_fp16.h>

#define BATCH 8
#define NSEQ 1024
#define DIMM 448
#define NHEAD 7
#define HDIM 64
#define MROWS (BATCH*NSEQ)   // 8192
#define KDIM 448
#define SCALE_F 0.125f
// Padded region stride (shorts) for packed K/V/bias streams.
#define PSTR 66048

typedef short short8 __attribute__((ext_vector_type(8)));
typedef float floatx16 __attribute__((ext_vector_type(16)));

#define MFMA32(a,b,c) __builtin_amdgcn_mfma_f32_32x32x16_bf16(a,b,c,0,0,0)

__device__ __forceinline__ unsigned short f2bf(float f){
    __hip_bfloat16 h = __float2bfloat16(f);
    return *reinterpret_cast<unsigned short*>(&h);
}
__device__ __forceinline__ float bf2f(unsigned short u){
    __hip_bfloat16 h; *reinterpret_cast<unsigned short*>(&h) = u;
    return __bfloat162float(h);
}
__device__ __forceinline__ float h2f(unsigned short u){
    __half h; *reinterpret_cast<unsigned short*>(&h) = u;
    return __half2float(h);
}
__device__ __forceinline__ unsigned short f2h(float f){
    __half h = __float2half(f);
    return *reinterpret_cast<unsigned short*>(&h);
}

// ---------------------------------------------------------------------------
// prep_min: ONLY the conversions gemm1 depends on.
// ---------------------------------------------------------------------------
__global__ __launch_bounds__(256)
void prep_min(const float* __restrict__ x, const float* __restrict__ wqv,
              unsigned short* __restrict__ xh, unsigned short* __restrict__ wqvTh)
{
    const int bx = blockIdx.x, tid = threadIdx.x;
    if (bx < 3584) {                         // x -> bf16
        int i = bx*256 + tid;
        float4 v = ((const float4*)x)[i];
        ((ushort4*)xh)[i] = make_ushort4(f2bf(v.x), f2bf(v.y), f2bf(v.z), f2bf(v.w));
    } else {                                 // wqv transpose, single bf16
        int lid = (bx-3584)*4 + (tid>>6);    // 0..783 = kc(56) x ng(14)
        int kc = lid % 56, ng = lid / 56;
        int n = ng*64 + (tid&63);
        unsigned short h[8];
#pragma unroll
        for (int j = 0; j < 8; ++j) h[j] = f2bf(wqv[(size_t)(kc*8+j)*896 + n]);
        size_t o = (size_t)n*KDIM + kc*8;
        *(ushort4*)(wqvTh + o)     = make_ushort4(h[0],h[1],h[2],h[3]);
        *(ushort4*)(wqvTh + o + 4) = make_ushort4(h[4],h[5],h[6],h[7]);
    }
}

// ---------------------------------------------------------------------------
// gemm1_fused: gemm1 (448 blocks) + bias-prep (1792) + ek-pack (448) +
// wout-split (112) in ONE launch = 2800 blocks.
// ---------------------------------------------------------------------------
__global__ __launch_bounds__(256, 2)
void gemm1_fused(const unsigned short* __restrict__ Ah, const unsigned short* __restrict__ Bh,
                 const float* __restrict__ ek, const float* __restrict__ eb,
                 const float* __restrict__ wout,
                 unsigned short* __restrict__ qd, unsigned short* __restrict__ vTd,
                 unsigned short* __restrict__ ekh, unsigned short* __restrict__ bp,
                 unsigned short* __restrict__ woTh, unsigned short* __restrict__ woTl)
{
    __shared__ float T[2][64][33];
    const int bx = blockIdx.x, tid = threadIdx.x;

    if (bx < 448) {                          // ---- gemm1 (proven code) ----
        const int w = tid >> 6, lane = tid & 63;
        const int lq = lane & 31, lh = lane >> 5;
        const int xb = bx & 31, y = bx >> 5;
        const int m0 = (xb*4 + w) * 64;
        const int n0 = y * 64;
        const unsigned short* aB = Ah + (size_t)(m0 + lq)*KDIM + lh*8;
        const unsigned short* bB = Bh + (size_t)(n0 + lq)*KDIM + lh*8;

        floatx16 acc[2][2] = {};
        short8 aR[2][2][2], bR[2][2][2];
#define LD1(kt, par) {                                                        \
    _Pragma("unroll") for (int fm = 0; fm < 2; ++fm)                          \
    _Pragma("unroll") for (int c = 0; c < 2; ++c) {                           \
        aR[par][fm][c] = *(const short8*)(aB + (size_t)fm*32*KDIM + (kt)*32 + c*16); \
        bR[par][fm][c] = *(const short8*)(bB + (size_t)fm*32*KDIM + (kt)*32 + c*16); } }

        LD1(0, 0)
#pragma unroll
        for (int kt = 0; kt < 14; ++kt) {
            const int par = kt & 1;
            if (kt < 13) LD1(kt+1, par^1)
#pragma unroll
            for (int c = 0; c < 2; ++c)
#pragma unroll
                for (int fm = 0; fm < 2; ++fm)
#pragma unroll
                    for (int fn = 0; fn < 2; ++fn)
                        acc[fm][fn] = MFMA32(aR[par][fm][c], bR[par][fn][c], acc[fm][fn]);
        }
#undef LD1

        if (y < NHEAD) {
#pragma unroll
            for (int fm = 0; fm < 2; ++fm)
#pragma unroll
                for (int fn = 0; fn < 2; ++fn) {
                    const int d = fn*32 + lq;
#pragma unroll
                    for (int r = 0; r < 16; ++r) {
                        const int gm = m0 + fm*32 + (r&3) + 8*(r>>2) + 4*lh;
                        const int b = gm >> 10, ns = gm & 1023;
                        qd[((size_t)((b*NHEAD + y)*NSEQ + ns))*HDIM + d] = f2bf(acc[fm][fn][r]);
                    }
                }
        } else {
            const int head = y - NHEAD;
#pragma unroll
            for (int fm = 0; fm < 2; ++fm) {
                const int gm0 = m0 + fm*32;
                const int b = gm0 >> 10, mm = (gm0 & 1023) >> 5;
                unsigned short* base = vTd + (size_t)(b*NHEAD + head)*PSTR + (size_t)mm*2048;
#pragma unroll
                for (int fn = 0; fn < 2; ++fn)
#pragma unroll
                    for (int rq = 0; rq < 4; ++rq) {
                        const int u = (rq>>1)*2 + fn;
                        const int lanep = (rq&1)*32 + lq;
                        *(ushort4*)(base + u*512 + lanep*8 + 4*lh) = make_ushort4(
                            f2bf(acc[fm][fn][rq*4+0]), f2bf(acc[fm][fn][rq*4+1]),
                            f2bf(acc[fm][fn][rq*4+2]), f2bf(acc[fm][fn][rq*4+3]));
                    }
            }
        }
    } else if (bx < 2240) {                  // ---- bias prep (padded) ----
        const int sub = tid >> 7, st = tid & 127;
        const int lid = (bx-448)*2 + sub;    // 0..3583
        const int mt = lid & 31, qt = (lid>>5) & 15, h = lid >> 9;
#pragma unroll
        for (int it = 0; it < 4; ++it) {
            int idx = it*128 + st;
            int row = idx >> 3, c4 = (idx & 7)*4;
            float4 v = *(const float4*)(eb + ((size_t)(h*NSEQ + qt*64 + row))*NSEQ + mt*32 + c4);
            T[sub][row][c4+0]=v.x; T[sub][row][c4+1]=v.y;
            T[sub][row][c4+2]=v.z; T[sub][row][c4+3]=v.w;
        }
        __syncthreads();
        const int g2 = st >> 6, lane = st & 63;
        const int lq = lane & 31, quad = lane >> 5;
        const int q = g2*32 + lq;
        unsigned short* dst = bp + (size_t)(h*16 + qt)*PSTR
                            + (size_t)(mt*4 + g2*2)*512 + lane*8;
#pragma unroll
        for (int jj = 0; jj < 2; ++jj) {
            unsigned short o[8];
#pragma unroll
            for (int t = 0; t < 8; ++t) {
                int m = (t&3) + 8*(t>>2) + 16*jj + 4*quad;
                o[t] = f2h(T[sub][q][m] * SCALE_F);
            }
            *(ushort4*)(dst + jj*512)     = make_ushort4(o[0],o[1],o[2],o[3]);
            *(ushort4*)(dst + jj*512 + 4) = make_ushort4(o[4],o[5],o[6],o[7]);
        }
    } else if (bx < 2688) {                  // ---- ek -> kP (packed, padded) ----
        int i = (bx-2240)*256 + tid;         // 0..114687 chunk of 4 shorts
        const int h  = i >> 14, mm = (i >> 9) & 31, c = (i >> 7) & 3;
        const int ln = (i >> 1) & 63, jh = i & 1;
        const float* src = ek + ((size_t)(h*NSEQ) + mm*32 + (ln & 31))*HDIM
                              + c*16 + (ln >> 5)*8 + jh*4;
        float4 v = *(const float4*)src;
        unsigned short* dst = ekh + (size_t)h*PSTR + (size_t)(i & 16383)*4;
        *(ushort4*)dst = make_ushort4(f2bf(v.x), f2bf(v.y), f2bf(v.z), f2bf(v.w));
    } else {                                 // ---- wout transpose, split hi/lo ----
        int lid = (bx-2688)*4 + (tid>>6);    // 0..447 = kc(56) x ng(8)
        int kc = lid % 56, ng = lid / 56;
        int n = ng*64 + (tid&63);
        ushort4 h0={0,0,0,0}, h1={0,0,0,0}, l0={0,0,0,0}, l1={0,0,0,0};
        if (n < DIMM) {
            unsigned short h[8], l[8];
#pragma unroll
            for (int j = 0; j < 8; ++j) {
                float f = wout[(size_t)(kc*8+j)*DIMM + n];
                h[j] = f2bf(f); l[j] = f2bf(f - bf2f(h[j]));
            }
            h0 = make_ushort4(h[0],h[1],h[2],h[3]); h1 = make_ushort4(h[4],h[5],h[6],h[7]);
            l0 = make_ushort4(l[0],l[1],l[2],l[3]); l1 = make_ushort4(l[4],l[5],l[6],l[7]);
        }
        size_t o = (size_t)n*KDIM + kc*8;
        *(ushort4*)(woTh + o) = h0; *(ushort4*)(woTh + o + 4) = h1;
        *(ushort4*)(woTl + o) = l0; *(ushort4*)(woTl + o + 4) = l1;
    }
}

// ---------------------------------------------------------------------------
// attn_half: attn7t with the 32-m-tile loop SPLIT 2-WAY ACROSS BLOCKS.
// Per-wave body/register shape identical to attn7t (the proven 128-VGPR
// attractor); only the loop range (mBeg = half*16) and the epilogue change.
// 448 blocks -> 1.75 blocks/CU, per-wave serial chain /2. In-register P
// transpose (software-RNE pack + permlane32_swap), zero bank conflicts.
// Epilogue: coalesced fp32 partial stores. No fences (R13 lesson: device
// fences poison L2 on gfx950).
// ---------------------------------------------------------------------------
__global__ __launch_bounds__(256, 2)
void attn_half(const unsigned short* __restrict__ qh_g, const unsigned short* __restrict__ vTh,
               const unsigned short* __restrict__ ekh, const unsigned short* __restrict__ bp,
               float4* __restrict__ opart, float2* __restrict__ lspart)
{
    const int tid = threadIdx.x;
    const int w = tid >> 6, lane = tid & 63;
    const int lq = lane & 31, lh = lane >> 5;

    // bijective XCD swizzle: 448 blocks, 56 per XCD
    const int orig = blockIdx.x;
    const int wg = (orig & 7)*56 + (orig >> 3);
    const int half = wg & 1, bq = (wg >> 1) & 1, qt = (wg >> 2) & 15, head = wg >> 6;
    const int b = bq*4 + w;
    const int bh = b*NHEAD + head;
    const int mBeg = half*16;

    short8 qf[2][4];
#pragma unroll
    for (int g2 = 0; g2 < 2; ++g2)
#pragma unroll
        for (int c = 0; c < 4; ++c)
            qf[g2][c] = *(const short8*)(qh_g +
                ((size_t)(bh*NSEQ) + qt*64 + g2*32 + lq)*HDIM + c*16 + lh*8);

    const unsigned short* kB = ekh + (size_t)head*PSTR + lane*8;
    const unsigned short* vB = vTh + (size_t)bh*PSTR + lane*8;
    const unsigned short* bB = bp + (size_t)(head*16 + qt)*PSTR + lane*8;

    short8 kR[2][4], vR[2][4], bR[2][4];
#define PREF(J, par) { const int mm = ((J) < mBeg+16) ? (J) : mBeg;            \
    _Pragma("unroll") for (int c = 0; c < 4; ++c)                              \
        kR[par][c] = *(const short8*)(kB + (size_t)mm*2048 + c*512);           \
    _Pragma("unroll") for (int u = 0; u < 4; ++u)                              \
        vR[par][u] = *(const short8*)(vB + (size_t)mm*2048 + u*512);           \
    _Pragma("unroll") for (int u = 0; u < 4; ++u)                              \
        bR[par][u] = *(const short8*)(bB + (size_t)mm*2048 + u*512); }

    floatx16 O[2][2] = {};
    float ls[2] = {0.f, 0.f};

#define SEC(J, par, nxt) {                                                     \
    PREF((J)+1, nxt)                                                           \
    _Pragma("unroll") for (int g2 = 0; g2 < 2; ++g2) {                         \
        floatx16 S = {};                                                       \
        _Pragma("unroll") for (int c = 0; c < 4; ++c)                          \
            S = MFMA32(kR[par][c], qf[g2][c], S);                              \
        float pv[16];                                                          \
        _Pragma("unroll") for (int i = 0; i < 16; ++i) {                       \
            float bs = h2f((unsigned short)bR[par][g2*2 + (i>>3)][i&7]);       \
            pv[i] = __expf(fmaf(S[i], SCALE_F, bs));                           \
            ls[g2] += pv[i];                                                   \
        }                                                                      \
        unsigned wpk[8];                                                       \
        _Pragma("unroll") for (int u = 0; u < 8; ++u)                          \
            wpk[u] = (unsigned)f2bf(pv[2*u]) | ((unsigned)f2bf(pv[2*u+1]) << 16); \
        asm("v_permlane32_swap_b32 %0, %1" : "+v"(wpk[0]), "+v"(wpk[2]));      \
        asm("v_permlane32_swap_b32 %0, %1" : "+v"(wpk[1]), "+v"(wpk[3]));      \
        asm("v_permlane32_swap_b32 %0, %1" : "+v"(wpk[4]), "+v"(wpk[6]));      \
        asm("v_permlane32_swap_b32 %0, %1" : "+v"(wpk[5]), "+v"(wpk[7]));      \
        union U8 { unsigned u[4]; short8 s; };                                 \
        U8 pa0, pa1;                                                           \
        pa0.u[0]=wpk[0]; pa0.u[1]=wpk[1]; pa0.u[2]=wpk[2]; pa0.u[3]=wpk[3];    \
        pa1.u[0]=wpk[4]; pa1.u[1]=wpk[5]; pa1.u[2]=wpk[6]; pa1.u[3]=wpk[7];    \
        O[g2][0] = MFMA32(pa0.s, vR[par][0], O[g2][0]);                        \
        O[g2][1] = MFMA32(pa0.s, vR[par][1], O[g2][1]);                        \
        O[g2][0] = MFMA32(pa1.s, vR[par][2], O[g2][0]);                        \
        O[g2][1] = MFMA32(pa1.s, vR[par][3], O[g2][1]);                        \
    } }

    PREF(mBeg, 0)
    for (int jj = 0; jj < 8; ++jj) {
        SEC(mBeg+2*jj,   0, 1)
        SEC(mBeg+2*jj+1, 1, 0)
    }
#undef SEC
#undef PREF

    // partial store: O fragments as [chunk(16)][lane] float4 (coalesced),
    // raw per-lane ls as float2.
    const int tile = (head*16 + qt)*8 + b;
    const int wid = tile*2 + half;
    float4* ob = opart + (size_t)wid*1024;
#pragma unroll
    for (int g2 = 0; g2 < 2; ++g2)
#pragma unroll
        for (int fn = 0; fn < 2; ++fn)
#pragma unroll
            for (int r4 = 0; r4 < 4; ++r4)
                ob[((g2*2+fn)*4 + r4)*64 + lane] = make_float4(
                    O[g2][fn][r4*4+0], O[g2][fn][r4*4+1],
                    O[g2][fn][r4*4+2], O[g2][fn][r4*4+3]);
    lspart[(size_t)wid*64 + lane] = make_float2(ls[0], ls[1]);
}

// ---------------------------------------------------------------------------
// attn_combine: per tile, sum the two half-partials, fold l, normalize,
// write aoh/aol (identical mapping to attn7t's epilogue).
// grid 224 x 256: wave w handles tile blockIdx*4 + w.
// ---------------------------------------------------------------------------
__global__ __launch_bounds__(256, 2)
void attn_combine(const float4* __restrict__ opart, const float2* __restrict__ lspart,
                  unsigned short* __restrict__ aoh, unsigned short* __restrict__ aol)
{
    __shared__ float linv[4][2][32];
    const int tid = threadIdx.x;
    const int w = tid >> 6, lane = tid & 63;
    const int lq = lane & 31, lh = lane >> 5;

    const int t = blockIdx.x*4 + w;          // 0..895
    const int b = t & 7, qt = (t >> 3) & 15, head = t >> 7;

    const float2 la = lspart[(size_t)(t*2)*64 + lane];
    const float2 lb = lspart[(size_t)(t*2+1)*64 + lane];
    float ls0 = la.x + lb.x, ls1 = la.y + lb.y;
    float lt0 = ls0 + __shfl_xor(ls0, 32);
    float lt1 = ls1 + __shfl_xor(ls1, 32);
    if (lh == 0) { linv[w][0][lq] = 1.f/lt0; linv[w][1][lq] = 1.f/lt1; }

    const float4* oa = opart + (size_t)(t*2)*1024;
    const float4* ob = opart + (size_t)(t*2+1)*1024;
#pragma unroll
    for (int g2 = 0; g2 < 2; ++g2)
#pragma unroll
        for (int fn = 0; fn < 2; ++fn)
#pragma unroll
            for (int r4 = 0; r4 < 4; ++r4) {
                const int ch = ((g2*2+fn)*4 + r4)*64 + lane;
                float4 va = oa[ch], vb = ob[ch];
                float s[4] = {va.x+vb.x, va.y+vb.y, va.z+vb.z, va.w+vb.w};
#pragma unroll
                for (int j = 0; j < 4; ++j) {
                    const int qr = j + 8*r4 + 4*lh;
                    const float inv = linv[w][g2][qr];
                    const size_t o = ((size_t)(b*NSEQ) + qt*64 + g2*32 + qr)*DIMM
                                   + head*HDIM + fn*32 + lq;
                    float v = s[j]*inv;
                    unsigned short h0 = f2bf(v);
                    aoh[o] = h0;  aol[o] = f2bf(v - bf2f(h0));
                }
            }
}

// ---------------------------------------------------------------------------
// gemm2_grp: out = ao @ w_out + b_out, split-2 (3-term), REGISTER-ONLY.
// ---------------------------------------------------------------------------
__global__ __launch_bounds__(128, 2)
void gemm2_grp(const unsigned short* __restrict__ Ah, const unsigned short* __restrict__ Al,
               const unsigned short* __restrict__ Bh, const unsigned short* __restrict__ Bl,
               const float* __restrict__ bias, float* __restrict__ out)
{
    const int tid = threadIdx.x;
    const int w = tid >> 6, lane = tid & 63;
    const int lq = lane & 31, lh = lane >> 5;
    const int m0 = (blockIdx.x*2 + w) * 64;
    const int n0 = blockIdx.y * 64;
    const unsigned short* aBh = Ah + (size_t)(m0 + lq)*KDIM + lh*8;
    const unsigned short* aBl = Al + (size_t)(m0 + lq)*KDIM + lh*8;
    const unsigned short* bBh = Bh + (size_t)(n0 + lq)*KDIM + lh*8;
    const unsigned short* bBl = Bl + (size_t)(n0 + lq)*KDIM + lh*8;

    floatx16 acc[2][2] = {};
    short8 aH[2][2][2], aL[2][2][2], bH[2][2][2], bL[2][2][2];
#define LD2(kt, par) {                                                        \
    _Pragma("unroll") for (int fm = 0; fm < 2; ++fm)                          \
    _Pragma("unroll") for (int c = 0; c < 2; ++c) {                           \
        const size_t off = (size_t)fm*32*KDIM + (kt)*32 + c*16;               \
        aH[par][fm][c] = *(const short8*)(aBh + off);                         \
        aL[par][fm][c] = *(const short8*)(aBl + off);                         \
        bH[par][fm][c] = *(const short8*)(bBh + off);                         \
        bL[par][fm][c] = *(const short8*)(bBl + off); } }

    LD2(0, 0)
#pragma unroll
    for (int kt = 0; kt < 14; ++kt) {
        const int par = kt & 1;
        if (kt < 13) LD2(kt+1, par^1)
#pragma unroll
        for (int c = 0; c < 2; ++c)
#pragma unroll
            for (int fm = 0; fm < 2; ++fm)
#pragma unroll
                for (int fn = 0; fn < 2; ++fn) {
                    acc[fm][fn] = MFMA32(aH[par][fm][c], bH[par][fn][c], acc[fm][fn]);
                    acc[fm][fn] = MFMA32(aL[par][fm][c], bH[par][fn][c], acc[fm][fn]);
                    acc[fm][fn] = MFMA32(aH[par][fm][c], bL[par][fn][c], acc[fm][fn]);
                }
    }
#undef LD2

#pragma unroll
    for (int fm = 0; fm < 2; ++fm)
#pragma unroll
        for (int fn = 0; fn < 2; ++fn) {
            const int gn = n0 + fn*32 + lq;
            const float bv = bias[gn];
#pragma unroll
            for (int r = 0; r < 16; ++r) {
                const int gm = m0 + fm*32 + (r&3) + 8*(r>>2) + 4*lh;
                out[(size_t)gm*DIMM + gn] = acc[fm][fn][r] + bv;
            }
        }
}

// ---------------------------------------------------------------------------
extern "C" void kernel_launch(void* const* d_in, const int* in_sizes, int n_in,
                              void* d_out, int out_size, void* d_ws, size_t ws_size,
                              hipStream_t stream)
{
    const float* x    = (const float*)d_in[0];
    const float* wqv  = (const float*)d_in[1];
    const float* ek   = (const float*)d_in[2];
    const float* eb   = (const float*)d_in[3];
    const float* wout = (const float*)d_in[4];
    const float* bout = (const float*)d_in[5];
    float* out = (float*)d_out;

    const size_t MK = (size_t)MROWS*KDIM;        // 3,670,016
    unsigned short* p = (unsigned short*)d_ws;
    unsigned short* xh    = p;  p += MK;
    unsigned short* wqvTh = p;  p += (size_t)896*KDIM;
    unsigned short* woTh  = p;  p += (size_t)512*KDIM;
    unsigned short* woTl  = p;  p += (size_t)512*KDIM;
    unsigned short* ekh   = p;  p += (size_t)NHEAD*PSTR;             // kP padded
    unsigned short* qh    = p;  p += MK;
    unsigned short* vTh   = p;  p += (size_t)BATCH*NHEAD*PSTR;       // vP padded
    unsigned short* bp    = p;  p += (size_t)NHEAD*16*PSTR;          // fp16 padded
    unsigned short* aoh   = p;  p += MK;
    unsigned short* aol   = p;  p += MK;
    // fp32 partials (16B-aligned: preceding offsets are multiples of 8 shorts)
    float4* opart  = (float4*)p;                 // 1792 * 1024 float4 = 29.4 MB
    p += (size_t)1792*1024*8;
    float2* lspart = (float2*)p;                 // 1792 * 64 float2 = 0.9 MB
    p += (size_t)1792*64*4;

    prep_min<<<3780, 256, 0, stream>>>(x, wqv, xh, wqvTh);
    gemm1_fused<<<2800, 256, 0, stream>>>(xh, wqvTh, ek, eb, wout,
                                          qh, vTh, ekh, bp, woTh, woTl);
    attn_half<<<448, 256, 0, stream>>>(qh, vTh, ekh, bp, opart, lspart);
    attn_combine<<<224, 256, 0, stream>>>(opart, lspart, aoh, aol);
    gemm2_grp<<<dim3(64, 7), 128, 0, stream>>>(aoh, aol, woTh, woTl, bout, out);
}